// Round 8
// baseline (12.142 us; speedup 1.0000x reference)
//
#include <hip/hip_runtime.h>

#define NUM_Z 100
#define NUM_G 512
#define DIM   64
#define THREADS 1024
#define CHUNK 128            // nodes per pass; feat tile = 32 KB LDS
#define WIN 2048             // batch/z prefetch window (2 ints per thread each)

// Fallback only: wave-cooperative 64-ary lower_bound.
__device__ __forceinline__ int lower_bound_wave(const int* __restrict__ arr, int n,
                                                int target, int lane) {
    int lo = 0, len = n;
    while (len > 0) {
        int step = (len + 63) >> 6;
        int idx  = lo + lane * step;
        int v    = (idx < n) ? arr[idx] : 0x7fffffff;
        unsigned long long m = __ballot(v < target);
        int k = (int)__popcll(m);
        if (k == 0) break;
        int rem = k * step; if (rem > len) rem = len;
        int hi  = lo + rem;
        lo += (k - 1) * step + 1;
        len = hi - lo;
    }
    return lo;
}

// One block per graph. Single-round-trip head: prefetch a 2048-wide window of
// batch+z around the statistically-known segment position; start/end from
// in-register ballots; z served from LDS. Then counting-sort (1-wave fused
// scan) + LDS-staged balanced gather as before.
__global__ __launch_bounds__(THREADS) void anp_win_kernel(
    const float4* __restrict__ feat,   // [N*16] quads of [N,64] features
    const int*    __restrict__ z,      // [N] in [1,100]
    const int*    __restrict__ batch,  // [N] sorted graph ids
    float*        __restrict__ pooled, // [G, 100*64]
    int n)
{
    __shared__ float4 tile[CHUNK * 16];      // 32 KB node-ordered feature rows
    __shared__ int zwin[WIN];                // 8 KB  (z-1 over the window)
    __shared__ int hist[128];
    __shared__ int pref[NUM_Z + 1];          // exclusive bin offsets
    __shared__ int cursor[NUM_Z];
    __shared__ unsigned short idx_sorted[CHUNK];
    __shared__ int Lpart[16], Epart[16];
    __shared__ int sbf, sbl;
    __shared__ int sb[2];

    const int g    = blockIdx.x;
    const int tid  = threadIdx.x;
    const int wave = tid >> 6;
    const int lane = tid & 63;
    const int grp  = tid >> 4;               // gather groups 0..49 active
    const int q    = tid & 15;
    const int b0   = 2 * grp;

    // ---- head: one round-trip window prefetch ----
    int wbase = (int)(((long long)g * n) / NUM_G) - 960;
    int wmax  = n - WIN; if (wmax < 0) wmax = 0;
    if (wbase < 0) wbase = 0;
    if (wbase > wmax) wbase = wmax;

    const int i0 = wbase + tid, i1 = wbase + tid + THREADS;
    int bv0 = (i0 < n) ? batch[i0] : 0x7fffffff;
    int bv1 = (i1 < n) ? batch[i1] : 0x7fffffff;
    int zv0 = (i0 < n) ? z[i0] : 1;
    int zv1 = (i1 < n) ? z[i1] : 1;

    if (tid < 128) hist[tid] = 0;
    zwin[tid]           = zv0 - 1;
    zwin[tid + THREADS] = zv1 - 1;
    {
        int l = __popcll(__ballot(bv0 < g))     + __popcll(__ballot(bv1 < g));
        int e = __popcll(__ballot(bv0 < g + 1)) + __popcll(__ballot(bv1 < g + 1));
        if (lane == 0) { Lpart[wave] = l; Epart[wave] = e; }
    }
    if (tid == 0)           sbf = bv0;       // batch[wbase]
    if (tid == THREADS - 1) sbl = bv1;       // batch[wbase+2047] (or sentinel)
    __syncthreads();                         // B1

    // reduce the 16 per-wave partials: 2 LDS broadcasts + 4 shfl_xor + 2 shfl
    int v = 0;
    if (lane < 16)      v = Lpart[lane];
    else if (lane < 32) v = Epart[lane - 16];
    v += __shfl_xor(v, 1, 64); v += __shfl_xor(v, 2, 64);
    v += __shfl_xor(v, 4, 64); v += __shfl_xor(v, 8, 64);
    const int L = __shfl(v, 0, 64);
    const int E = __shfl(v, 16, 64);

    const bool valid = ((wbase == 0) || (sbf < g)) &&
                       ((wbase + WIN >= n) || (sbl > g));   // block-uniform
    int start, end;
    if (valid) {
        start = wbase + L; end = wbase + E;
    } else {                                 // rare/never: exact fallback
        if (wave < 2) {
            int r = lower_bound_wave(batch, n, g + wave, lane);
            if (lane == 0) sb[wave] = r;
        }
        __syncthreads();
        start = sb[0]; end = sb[1];
    }
    const int cnt = end - start;
    const int dlt = start - wbase;

    float4 a0 = make_float4(0.f, 0.f, 0.f, 0.f);
    float4 a1 = make_float4(0.f, 0.f, 0.f, 0.f);
    const int jrow = tid >> 4;               // rows this thread stages

    for (int cs = start; cs < end; cs += CHUNK) {
        const int m = min(CHUNK, end - cs);

        // issue staging loads EARLY (hide under sort chain)
        float4 s0, s1;
        const bool h0 = (jrow      < m);
        const bool h1 = (jrow + 64 < m);
        if (h0) s0 = feat[(size_t)(cs + jrow)      * 16 + q];
        if (h1) s1 = feat[(size_t)(cs + jrow + 64) * 16 + q];

        int zb = 0;
        if (tid < m) {
            zb = valid ? zwin[dlt + (cs - start) + tid] : (z[cs + tid] - 1);
            atomicAdd(&hist[zb], 1);
        }
        __syncthreads();                     // B2

        if (wave == 0) {                     // fused dual 64-entry shfl scan
            int h0v = hist[lane], h1v = hist[64 + lane];
            int i0v = h0v, i1v = h1v;
            #pragma unroll
            for (int d = 1; d < 64; d <<= 1) {
                int t0 = __shfl_up(i0v, d, 64);
                int t1 = __shfl_up(i1v, d, 64);
                if (lane >= d) { i0v += t0; i1v += t1; }
            }
            const int e0 = i0v - h0v, e1 = i1v - h1v;
            const int tot0 = __shfl(i0v, 63, 64);
            pref[lane]   = e0;               // exclusive offsets, bins 0..63
            cursor[lane] = e0;
            if (lane <= 36) pref[64 + lane]   = tot0 + e1;   // bins 64..100
            if (lane <= 35) cursor[64 + lane] = tot0 + e1;
        }
        __syncthreads();                     // B3

        // late LDS write of staged rows (loads were in flight) + index scatter
        if (h0) tile[jrow * 16 + q]        = s0;
        if (h1) tile[(jrow + 64) * 16 + q] = s1;
        if (tid < m) {
            int p = atomicAdd(&cursor[zb], 1);
            idx_sorted[p] = (unsigned short)(tid | ((zb & 1) << 15));
        }
        __syncthreads();                     // B4

        // balanced gather from LDS
        if (grp < 50) {
            const int off = pref[b0];
            const int c   = pref[b0 + 2] - off;
            for (int base = 0; base < c; base += 16) {
                const int nb = min(16, c - base);
                int myraw = (q < nb) ? (int)idx_sorted[off + base + q] : 0;
                #pragma unroll 4
                for (int j = 0; j < nb; ++j) {
                    int raw  = __shfl(myraw, ((lane >> 4) << 4) + j, 64);
                    int nd   = raw & 0x7fff;
                    float pm = (float)(raw >> 15);   // 0 -> b0, 1 -> b0+1
                    float4 vv = tile[nd * 16 + q];
                    float m0 = 1.0f - pm;
                    a0.x = fmaf(vv.x, m0, a0.x); a0.y = fmaf(vv.y, m0, a0.y);
                    a0.z = fmaf(vv.z, m0, a0.z); a0.w = fmaf(vv.w, m0, a0.w);
                    a1.x = fmaf(vv.x, pm, a1.x); a1.y = fmaf(vv.y, pm, a1.y);
                    a1.z = fmaf(vv.z, pm, a1.z); a1.w = fmaf(vv.w, pm, a1.w);
                }
            }
        }
        if (cs + CHUNK < end) {              // rare multi-chunk: recycle LDS
            __syncthreads();
            if (tid < 128) hist[tid] = 0;
            __syncthreads();
        }
    }

    if (grp < 50) {
        const float s = 1.0f / (float)(cnt > 1 ? cnt : 1);
        float4* outv = (float4*)(pooled + (size_t)g * (NUM_Z * DIM));
        outv[(b0 + 0) * 16 + q] = make_float4(a0.x*s, a0.y*s, a0.z*s, a0.w*s);
        outv[(b0 + 1) * 16 + q] = make_float4(a1.x*s, a1.y*s, a1.z*s, a1.w*s);
    }
}

extern "C" void kernel_launch(void* const* d_in, const int* in_sizes, int n_in,
                              void* d_out, int out_size, void* d_ws, size_t ws_size,
                              hipStream_t stream) {
    const float* feat  = (const float*)d_in[0];
    const int*   z     = (const int*)d_in[1];
    const int*   batch = (const int*)d_in[2];
    float* pooled = (float*)d_out;
    const int n = in_sizes[0] / DIM;   // 50000

    anp_win_kernel<<<NUM_G, THREADS, 0, stream>>>(
        (const float4*)feat, z, batch, pooled, n);
}